// Round 1
// baseline (912.160 us; speedup 1.0000x reference)
//
#include <hip/hip_runtime.h>
#include <hip/hip_bf16.h>

typedef short bf16x8 __attribute__((ext_vector_type(8)));
typedef float f32x4 __attribute__((ext_vector_type(4)));

#define NH 12
#define SEQ 1792
#define DMODEL 1536
#define HD 128

static __device__ __forceinline__ void gload16(const void* g, void* l) {
  __builtin_amdgcn_global_load_lds((const __attribute__((address_space(1))) void*)g,
                                   (__attribute__((address_space(3))) void*)l, 16, 0, 0);
}

static __device__ __forceinline__ short f2bf(float x) {
  __hip_bfloat16 h = __float2bfloat16(x);
  return *reinterpret_cast<short*>(&h);
}

// ---------- fp32 -> bf16 cast, x4 vectorized ----------
__global__ __launch_bounds__(256) void cast_kernel(const float* __restrict__ src,
                                                   __hip_bfloat16* __restrict__ dst, int n4) {
  int i = blockIdx.x * 256 + threadIdx.x;
  if (i >= n4) return;
  float4 v = reinterpret_cast<const float4*>(src)[i];
  short4 r;
  r.x = f2bf(v.x); r.y = f2bf(v.y); r.z = f2bf(v.z); r.w = f2bf(v.w);
  reinterpret_cast<short4*>(dst)[i] = r;
}

// ---------- 128x128 bf16 GEMM, B^T layout (C = A @ B^T), m97 structure ----------
// MODE 0: QKV epilogue (bias + scatter q/k row-major per-head, v transposed)
// MODE 1: fp32 out epilogue (bias)
template<int MODE>
__global__ __launch_bounds__(256) void gemm_bt(
    const __hip_bfloat16* __restrict__ A, const __hip_bfloat16* __restrict__ B, int K,
    const float* __restrict__ bq, const float* __restrict__ bk, const float* __restrict__ bv,
    __hip_bfloat16* __restrict__ qbuf, __hip_bfloat16* __restrict__ kbuf,
    __hip_bfloat16* __restrict__ vt,
    const float* __restrict__ bo, float* __restrict__ outp)
{
  __shared__ __hip_bfloat16 Abuf[2][128 * 32];
  __shared__ __hip_bfloat16 Bbuf[2][128 * 32];
  const int tid = threadIdx.x;
  const int l = tid & 63, w = tid >> 6;
  const int lr = l & 15, lg = l >> 4;
  const int wr = w >> 1, wc = w & 1;
  const int m0 = blockIdx.y * 128, n0 = blockIdx.x * 128;
  const int nK = K >> 5;

  f32x4 acc[4][4] = {};

  auto stage = [&](int buf, int kk) {
#pragma unroll
    for (int q2 = 0; q2 < 2; ++q2) {
      int flat = q2 * 256 + tid;      // 16B chunk id, 512 chunks per 8KB tile
      int row = flat >> 2;            // 64B (32 bf16) per row
      int kb16 = (flat & 3) * 16;     // byte within row
      const __hip_bfloat16* ga = A + (size_t)(m0 + row) * K + kk + (kb16 >> 1);
      gload16(ga, &Abuf[buf][(q2 * 256 + w * 64) * 8]);
      const __hip_bfloat16* gb = B + (size_t)(n0 + row) * K + kk + (kb16 >> 1);
      gload16(gb, &Bbuf[buf][(q2 * 256 + w * 64) * 8]);
    }
  };

  stage(0, 0);
  for (int kt = 0; kt < nK; ++kt) {
    __syncthreads();                       // vmcnt(0) drain: buf[kt&1] ready
    if (kt + 1 < nK) stage((kt + 1) & 1, (kt + 1) * 32);
    const __hip_bfloat16* Ab = Abuf[kt & 1];
    const __hip_bfloat16* Bb = Bbuf[kt & 1];
    bf16x8 af[4], bf[4];
#pragma unroll
    for (int fi = 0; fi < 4; ++fi)
      af[fi] = *reinterpret_cast<const bf16x8*>(&Ab[(wr * 64 + fi * 16 + lr) * 32 + lg * 8]);
#pragma unroll
    for (int fj = 0; fj < 4; ++fj)
      bf[fj] = *reinterpret_cast<const bf16x8*>(&Bb[(wc * 64 + fj * 16 + lr) * 32 + lg * 8]);
#pragma unroll
    for (int fi = 0; fi < 4; ++fi)
#pragma unroll
      for (int fj = 0; fj < 4; ++fj)
        acc[fi][fj] = __builtin_amdgcn_mfma_f32_16x16x32_bf16(af[fi], bf[fj], acc[fi][fj], 0, 0, 0);
  }

  if (MODE == 0) {
#pragma unroll
    for (int fj = 0; fj < 4; ++fj) {
      int ncol = n0 + wc * 64 + fj * 16 + lr;     // 0..4607
      int which = ncol / DMODEL;                  // 0=q 1=k 2=v (uniform per block)
      int cc = ncol - which * DMODEL;
      int hh = cc >> 7, dd = cc & 127;
      float bias = (which == 0 ? bq : which == 1 ? bk : bv)[cc];
#pragma unroll
      for (int fi = 0; fi < 4; ++fi)
#pragma unroll
        for (int r = 0; r < 4; ++r) {
          int rowg = m0 + wr * 64 + fi * 16 + lg * 4 + r;
          int bbb = rowg / SEQ;
          int sr = rowg - bbb * SEQ;
          __hip_bfloat16 hv = __float2bfloat16(acc[fi][fj][r] + bias);
          if (which == 0)
            qbuf[(((size_t)(bbb * NH + hh)) * SEQ + sr) * HD + dd] = hv;
          else if (which == 1)
            kbuf[(((size_t)(bbb * NH + hh)) * SEQ + sr) * HD + dd] = hv;
          else
            vt[(((size_t)(bbb * NH + hh)) * HD + dd) * SEQ + sr] = hv;
        }
    }
  } else {
#pragma unroll
    for (int fj = 0; fj < 4; ++fj) {
      int ncol = n0 + wc * 64 + fj * 16 + lr;
      float bias = bo[ncol];
#pragma unroll
      for (int fi = 0; fi < 4; ++fi)
#pragma unroll
        for (int r = 0; r < 4; ++r) {
          int rowg = m0 + wr * 64 + fi * 16 + lg * 4 + r;
          outp[(size_t)rowg * DMODEL + ncol] = acc[fi][fj][r] + bias;
        }
    }
  }
}

// ---------- RMSNorm (full-D) + 3D-grid RoPE, in-place on q,k ----------
__global__ __launch_bounds__(256) void rmsrope_kernel(
    __hip_bfloat16* __restrict__ qb, __hip_bfloat16* __restrict__ kb,
    const float* __restrict__ gq, const float* __restrict__ gk,
    const float* __restrict__ fc, const float* __restrict__ fs,
    const int* __restrict__ gsz, const int* __restrict__ nmod)
{
  const int bs = blockIdx.x;
  const int b = bs / SEQ, s = bs - b * SEQ;
  const int t = threadIdx.x;
  const int f = gsz[0], h = gsz[1], wd = gsz[2];
  const int mm = nmod[0];
  const int seq_per = f * h * wd;
  int total_len = seq_per * mm; if (total_len > SEQ) total_len = SEQ;
  const bool dorope = s < total_len;
  int fi = 0, hi2 = 0, wi = 0;
  if (dorope) {
    int p = s % seq_per;
    fi = p / (h * wd);
    int rem = p - fi * (h * wd);
    hi2 = rem / wd;
    wi = rem - hi2 * wd;
  }
  float qv[3][2], kv[3][2];
  float sq = 0.f, sk = 0.f;
#pragma unroll
  for (int r = 0; r < 3; ++r) {
    int pi = t + r * 256;                 // pair index 0..767
    int head = pi >> 6;
    int dd = (pi & 63) * 2;
    size_t addr = (((size_t)(b * NH + head)) * SEQ + s) * HD + dd;
    __hip_bfloat162 q2 = *reinterpret_cast<const __hip_bfloat162*>(&qb[addr]);
    __hip_bfloat162 k2 = *reinterpret_cast<const __hip_bfloat162*>(&kb[addr]);
    qv[r][0] = __bfloat162float(q2.x); qv[r][1] = __bfloat162float(q2.y);
    kv[r][0] = __bfloat162float(k2.x); kv[r][1] = __bfloat162float(k2.y);
    sq += qv[r][0] * qv[r][0] + qv[r][1] * qv[r][1];
    sk += kv[r][0] * kv[r][0] + kv[r][1] * kv[r][1];
  }
#pragma unroll
  for (int off = 1; off < 64; off <<= 1) {
    sq += __shfl_xor(sq, off);
    sk += __shfl_xor(sk, off);
  }
  __shared__ float red[2][4];
  if ((t & 63) == 0) { red[0][t >> 6] = sq; red[1][t >> 6] = sk; }
  __syncthreads();
  float tq = red[0][0] + red[0][1] + red[0][2] + red[0][3];
  float tk = red[1][0] + red[1][1] + red[1][2] + red[1][3];
  float rq = rsqrtf(tq * (1.0f / DMODEL) + 1e-6f);
  float rk = rsqrtf(tk * (1.0f / DMODEL) + 1e-6f);
#pragma unroll
  for (int r = 0; r < 3; ++r) {
    int pi = t + r * 256;
    int head = pi >> 6;
    int dd = (pi & 63) * 2;
    int col = pi * 2;
    size_t addr = (((size_t)(b * NH + head)) * SEQ + s) * HD + dd;
    float q0 = qv[r][0] * rq * gq[col], q1 = qv[r][1] * rq * gq[col + 1];
    float k0 = kv[r][0] * rk * gk[col], k1 = kv[r][1] * rk * gk[col + 1];
    if (dorope) {
      int j = pi & 63;                    // channel in [0,64); ct=22, ct+ch=43 (c=64)
      int row = (j < 22) ? fi : (j < 43) ? hi2 : wi;
      float co = fc[row * 64 + j], si = fs[row * 64 + j];
      float a;
      a = q0 * co - q1 * si; q1 = q0 * si + q1 * co; q0 = a;
      a = k0 * co - k1 * si; k1 = k0 * si + k1 * co; k0 = a;
    }
    __hip_bfloat162 oq, ok;
    oq.x = __float2bfloat16(q0); oq.y = __float2bfloat16(q1);
    ok.x = __float2bfloat16(k0); ok.y = __float2bfloat16(k1);
    *reinterpret_cast<__hip_bfloat162*>(&qb[addr]) = oq;
    *reinterpret_cast<__hip_bfloat162*>(&kb[addr]) = ok;
  }
}

// ---------- flash attention: 4 waves, 64 q-rows/block, KVBLK=64 ----------
__global__ __launch_bounds__(256) void attn_kernel(
    const __hip_bfloat16* __restrict__ qb, const __hip_bfloat16* __restrict__ kbuf,
    const __hip_bfloat16* __restrict__ vt, const int* __restrict__ seq_lens,
    __hip_bfloat16* __restrict__ ob)
{
  const int qt = blockIdx.x, hh = blockIdx.y, bbb = blockIdx.z;
  const int bh = bbb * NH + hh;
  const int tid = threadIdx.x;
  const int w = tid >> 6, l = tid & 63;
  const int lr = l & 15, lg = l >> 4;
  const int sl = seq_lens[bbb];
  const __hip_bfloat16* Q = qb + (size_t)bh * SEQ * HD;
  const __hip_bfloat16* Kp = kbuf + (size_t)bh * SEQ * HD;
  const __hip_bfloat16* Vp = vt + (size_t)bh * HD * SEQ;   // [128][1792]
  const int q0 = qt * 64 + w * 16;

  bf16x8 aq[4];
#pragma unroll
  for (int kc = 0; kc < 4; ++kc)
    aq[kc] = *reinterpret_cast<const bf16x8*>(&Q[(size_t)(q0 + lr) * HD + kc * 32 + lg * 8]);

  f32x4 oacc[8] = {};
  float mrow[4] = {-3e38f, -3e38f, -3e38f, -3e38f};
  float lrow[4] = {0.f, 0.f, 0.f, 0.f};
  __shared__ float Pl[4][16][68];          // per-wave P tile, padded
  const int nkt = (sl + 63) >> 6;
  const float scale = 0.08838834764831845f; // 1/sqrt(128)

  for (int kt = 0; kt < nkt; ++kt) {
    const int k0 = kt * 64;
    f32x4 sa[4] = {};
#pragma unroll
    for (int cb = 0; cb < 4; ++cb)
#pragma unroll
      for (int kc = 0; kc < 4; ++kc) {
        bf16x8 bk8 = *reinterpret_cast<const bf16x8*>(
            &Kp[(size_t)(k0 + cb * 16 + lr) * HD + kc * 32 + lg * 8]);
        sa[cb] = __builtin_amdgcn_mfma_f32_16x16x32_bf16(aq[kc], bk8, sa[cb], 0, 0, 0);
      }
    float pv[4][4];
    float mx[4] = {-3e38f, -3e38f, -3e38f, -3e38f};
#pragma unroll
    for (int cb = 0; cb < 4; ++cb) {
      int colk = k0 + cb * 16 + lr;
      bool valid = colk < sl;
#pragma unroll
      for (int r = 0; r < 4; ++r) {
        float sv = sa[cb][r] * scale;
        sv = valid ? sv : -3e38f;
        pv[cb][r] = sv;
        mx[r] = fmaxf(mx[r], sv);
      }
    }
#pragma unroll
    for (int off = 1; off < 16; off <<= 1)
#pragma unroll
      for (int r = 0; r < 4; ++r)
        mx[r] = fmaxf(mx[r], __shfl_xor(mx[r], off));
    float alpha[4];
#pragma unroll
    for (int r = 0; r < 4; ++r) {
      float mn = fmaxf(mrow[r], mx[r]);
      alpha[r] = __expf(mrow[r] - mn);
      mrow[r] = mn;
    }
    float rs[4] = {0.f, 0.f, 0.f, 0.f};
#pragma unroll
    for (int cb = 0; cb < 4; ++cb)
#pragma unroll
      for (int r = 0; r < 4; ++r) {
        float e = __expf(pv[cb][r] - mrow[r]);
        pv[cb][r] = e;
        rs[r] += e;
      }
#pragma unroll
    for (int off = 1; off < 16; off <<= 1)
#pragma unroll
      for (int r = 0; r < 4; ++r)
        rs[r] += __shfl_xor(rs[r], off);
#pragma unroll
    for (int r = 0; r < 4; ++r)
      lrow[r] = lrow[r] * alpha[r] + rs[r];
#pragma unroll
    for (int df = 0; df < 8; ++df)
#pragma unroll
      for (int r = 0; r < 4; ++r)
        oacc[df][r] *= alpha[r];

    __syncthreads();                      // Pl reuse fence
#pragma unroll
    for (int cb = 0; cb < 4; ++cb)
#pragma unroll
      for (int r = 0; r < 4; ++r)
        Pl[w][lg * 4 + r][cb * 16 + lr] = pv[cb][r];
    __syncthreads();                      // write->read fence (D-frag -> A-frag relayout)

#pragma unroll
    for (int kc2 = 0; kc2 < 2; ++kc2) {
      bf16x8 pa;
#pragma unroll
      for (int j = 0; j < 8; ++j)
        pa[j] = f2bf(Pl[w][lr][kc2 * 32 + lg * 8 + j]);
#pragma unroll
      for (int df = 0; df < 8; ++df) {
        bf16x8 bv8 = *reinterpret_cast<const bf16x8*>(
            &Vp[(size_t)(df * 16 + lr) * SEQ + k0 + kc2 * 32 + lg * 8]);
        oacc[df] = __builtin_amdgcn_mfma_f32_16x16x32_bf16(pa, bv8, oacc[df], 0, 0, 0);
      }
    }
  }

  float inv[4];
#pragma unroll
  for (int r = 0; r < 4; ++r) inv[r] = 1.0f / lrow[r];
#pragma unroll
  for (int df = 0; df < 8; ++df)
#pragma unroll
    for (int r = 0; r < 4; ++r) {
      int srow = q0 + lg * 4 + r;
      int dcol = hh * HD + df * 16 + lr;
      ob[((size_t)bbb * SEQ + srow) * DMODEL + dcol] = __float2bfloat16(oacc[df][r] * inv[r]);
    }
}

// ---------- launch ----------
extern "C" void kernel_launch(void* const* d_in, const int* in_sizes, int n_in,
                              void* d_out, int out_size, void* d_ws, size_t ws_size,
                              hipStream_t stream) {
  const float* x   = (const float*)d_in[0];
  const int* seq_lens   = (const int*)d_in[1];
  const int* grid_sizes = (const int*)d_in[2];
  const float* fc  = (const float*)d_in[3];
  const float* fs  = (const float*)d_in[4];
  const float* Wq  = (const float*)d_in[5];
  const float* bq  = (const float*)d_in[6];
  const float* Wk  = (const float*)d_in[7];
  const float* bk  = (const float*)d_in[8];
  const float* Wv  = (const float*)d_in[9];
  const float* bv  = (const float*)d_in[10];
  const float* Wo  = (const float*)d_in[11];
  const float* bo  = (const float*)d_in[12];
  const float* gq  = (const float*)d_in[13];
  const float* gk  = (const float*)d_in[14];
  const int* nmod  = (const int*)d_in[15];
  float* out = (float*)d_out;

  char* ws = (char*)d_ws;
  // byte offsets (all 16B aligned)
  __hip_bfloat16* xb   = (__hip_bfloat16*)(ws + 0);           // [7168][1536]  (also O later)
  __hip_bfloat16* wb   = (__hip_bfloat16*)(ws + 22020096);    // [4608][1536]
  __hip_bfloat16* wob  = (__hip_bfloat16*)(ws + 36175872);    // [1536][1536]
  __hip_bfloat16* qbuf = (__hip_bfloat16*)(ws + 40894464);    // [48][1792][128]
  __hip_bfloat16* kbuf = (__hip_bfloat16*)(ws + 62914560);    // [48][1792][128]
  __hip_bfloat16* vtb  = (__hip_bfloat16*)(ws + 84934656);    // [48][128][1792]
  __hip_bfloat16* ob   = xb;                                  // O reuses xb region

  // casts
  cast_kernel<<<(11010048 / 4 + 255) / 256, 256, 0, stream>>>(x, xb, 11010048 / 4);
  cast_kernel<<<(2359296 / 4 + 255) / 256, 256, 0, stream>>>(Wq, wb, 2359296 / 4);
  cast_kernel<<<(2359296 / 4 + 255) / 256, 256, 0, stream>>>(Wk, wb + 2359296, 2359296 / 4);
  cast_kernel<<<(2359296 / 4 + 255) / 256, 256, 0, stream>>>(Wv, wb + 4718592, 2359296 / 4);
  cast_kernel<<<(2359296 / 4 + 255) / 256, 256, 0, stream>>>(Wo, wob, 2359296 / 4);

  // QKV projection (M=7168, N=4608, K=1536) with bias + scatter epilogue
  gemm_bt<0><<<dim3(36, 56), 256, 0, stream>>>(xb, wb, 1536, bq, bk, bv,
                                               qbuf, kbuf, vtb, nullptr, nullptr);
  // RMS + RoPE in-place on q,k
  rmsrope_kernel<<<7168, 256, 0, stream>>>(qbuf, kbuf, gq, gk, fc, fs, grid_sizes, nmod);
  // flash attention -> O (bf16, reuses xb region)
  attn_kernel<<<dim3(28, 12, 4), 256, 0, stream>>>(qbuf, kbuf, vtb, seq_lens, ob);
  // output projection (M=7168, N=1536, K=1536) + bias -> fp32 out
  gemm_bt<1><<<dim3(12, 56), 256, 0, stream>>>(ob, wob, 1536, nullptr, nullptr, nullptr,
                                               nullptr, nullptr, nullptr, bo, out);
}

// Round 2
// 664.815 us; speedup vs baseline: 1.3721x; 1.3721x over previous
//
#include <hip/hip_runtime.h>
#include <hip/hip_bf16.h>

typedef short bf16x8 __attribute__((ext_vector_type(8)));
typedef float f32x4 __attribute__((ext_vector_type(4)));

#define NH 12
#define SEQ 1792
#define DMODEL 1536
#define HD 128

static __device__ __forceinline__ void gload16(const void* g, void* l) {
  __builtin_amdgcn_global_load_lds((const __attribute__((address_space(1))) void*)g,
                                   (__attribute__((address_space(3))) void*)l, 16, 0, 0);
}

static __device__ __forceinline__ short f2bf(float x) {
  __hip_bfloat16 h = __float2bfloat16(x);
  return *reinterpret_cast<short*>(&h);
}

// ---------- fp32 -> bf16 cast, x4 vectorized ----------
__global__ __launch_bounds__(256) void cast_kernel(const float* __restrict__ src,
                                                   __hip_bfloat16* __restrict__ dst, int n4) {
  int i = blockIdx.x * 256 + threadIdx.x;
  if (i >= n4) return;
  float4 v = reinterpret_cast<const float4*>(src)[i];
  short4 r;
  r.x = f2bf(v.x); r.y = f2bf(v.y); r.z = f2bf(v.z); r.w = f2bf(v.w);
  reinterpret_cast<short4*>(dst)[i] = r;
}

// ---------- 128x128 bf16 GEMM, B^T layout (C = A @ B^T), m97 structure ----------
template<int MODE>
__global__ __launch_bounds__(256) void gemm_bt(
    const __hip_bfloat16* __restrict__ A, const __hip_bfloat16* __restrict__ B, int K,
    const float* __restrict__ bq, const float* __restrict__ bk, const float* __restrict__ bv,
    __hip_bfloat16* __restrict__ qbuf, __hip_bfloat16* __restrict__ kbuf,
    __hip_bfloat16* __restrict__ vt,
    const float* __restrict__ bo, float* __restrict__ outp)
{
  __shared__ __hip_bfloat16 Abuf[2][128 * 32];
  __shared__ __hip_bfloat16 Bbuf[2][128 * 32];
  const int tid = threadIdx.x;
  const int l = tid & 63, w = tid >> 6;
  const int lr = l & 15, lg = l >> 4;
  const int wr = w >> 1, wc = w & 1;
  const int m0 = blockIdx.y * 128, n0 = blockIdx.x * 128;
  const int nK = K >> 5;

  f32x4 acc[4][4] = {};

  auto stage = [&](int buf, int kk) {
#pragma unroll
    for (int q2 = 0; q2 < 2; ++q2) {
      int flat = q2 * 256 + tid;
      int row = flat >> 2;
      int kb16 = (flat & 3) * 16;
      const __hip_bfloat16* ga = A + (size_t)(m0 + row) * K + kk + (kb16 >> 1);
      gload16(ga, &Abuf[buf][(q2 * 256 + w * 64) * 8]);
      const __hip_bfloat16* gb = B + (size_t)(n0 + row) * K + kk + (kb16 >> 1);
      gload16(gb, &Bbuf[buf][(q2 * 256 + w * 64) * 8]);
    }
  };

  stage(0, 0);
  for (int kt = 0; kt < nK; ++kt) {
    __syncthreads();
    if (kt + 1 < nK) stage((kt + 1) & 1, (kt + 1) * 32);
    const __hip_bfloat16* Ab = Abuf[kt & 1];
    const __hip_bfloat16* Bb = Bbuf[kt & 1];
    bf16x8 af[4], bfr[4];
#pragma unroll
    for (int fi = 0; fi < 4; ++fi)
      af[fi] = *reinterpret_cast<const bf16x8*>(&Ab[(wr * 64 + fi * 16 + lr) * 32 + lg * 8]);
#pragma unroll
    for (int fj = 0; fj < 4; ++fj)
      bfr[fj] = *reinterpret_cast<const bf16x8*>(&Bb[(wc * 64 + fj * 16 + lr) * 32 + lg * 8]);
#pragma unroll
    for (int fi = 0; fi < 4; ++fi)
#pragma unroll
      for (int fj = 0; fj < 4; ++fj)
        acc[fi][fj] = __builtin_amdgcn_mfma_f32_16x16x32_bf16(af[fi], bfr[fj], acc[fi][fj], 0, 0, 0);
  }

  if (MODE == 0) {
#pragma unroll
    for (int fj = 0; fj < 4; ++fj) {
      int ncol = n0 + wc * 64 + fj * 16 + lr;
      int which = ncol / DMODEL;
      int cc = ncol - which * DMODEL;
      int hh = cc >> 7, dd = cc & 127;
      float bias = (which == 0 ? bq : which == 1 ? bk : bv)[cc];
#pragma unroll
      for (int fi = 0; fi < 4; ++fi)
#pragma unroll
        for (int r = 0; r < 4; ++r) {
          int rowg = m0 + wr * 64 + fi * 16 + lg * 4 + r;
          int bbb = rowg / SEQ;
          int sr = rowg - bbb * SEQ;
          __hip_bfloat16 hv = __float2bfloat16(acc[fi][fj][r] + bias);
          if (which == 0)
            qbuf[(((size_t)(bbb * NH + hh)) * SEQ + sr) * HD + dd] = hv;
          else if (which == 1)
            kbuf[(((size_t)(bbb * NH + hh)) * SEQ + sr) * HD + dd] = hv;
          else
            vt[(((size_t)(bbb * NH + hh)) * HD + dd) * SEQ + sr] = hv;
        }
    }
  } else {
#pragma unroll
    for (int fj = 0; fj < 4; ++fj) {
      int ncol = n0 + wc * 64 + fj * 16 + lr;
      float bias = bo[ncol];
#pragma unroll
      for (int fi = 0; fi < 4; ++fi)
#pragma unroll
        for (int r = 0; r < 4; ++r) {
          int rowg = m0 + wr * 64 + fi * 16 + lg * 4 + r;
          outp[(size_t)rowg * DMODEL + ncol] = acc[fi][fj][r] + bias;
        }
    }
  }
}

// ---------- RMSNorm (full-D) + 3D-grid RoPE, in-place on q,k ----------
// q additionally pre-scaled by 1/sqrt(HD) so attention skips the scale.
__global__ __launch_bounds__(256) void rmsrope_kernel(
    __hip_bfloat16* __restrict__ qb, __hip_bfloat16* __restrict__ kb,
    const float* __restrict__ gq, const float* __restrict__ gk,
    const float* __restrict__ fc, const float* __restrict__ fs,
    const int* __restrict__ gsz, const int* __restrict__ nmod)
{
  const int bs = blockIdx.x;
  const int b = bs / SEQ, s = bs - b * SEQ;
  const int t = threadIdx.x;
  const int f = gsz[0], h = gsz[1], wd = gsz[2];
  const int mm = nmod[0];
  const int seq_per = f * h * wd;
  int total_len = seq_per * mm; if (total_len > SEQ) total_len = SEQ;
  const bool dorope = s < total_len;
  int fi = 0, hi2 = 0, wi = 0;
  if (dorope) {
    int p = s % seq_per;
    fi = p / (h * wd);
    int rem = p - fi * (h * wd);
    hi2 = rem / wd;
    wi = rem - hi2 * wd;
  }
  float qv[3][2], kv[3][2];
  float sq = 0.f, sk = 0.f;
#pragma unroll
  for (int r = 0; r < 3; ++r) {
    int pi = t + r * 256;
    int head = pi >> 6;
    int dd = (pi & 63) * 2;
    size_t addr = (((size_t)(b * NH + head)) * SEQ + s) * HD + dd;
    __hip_bfloat162 q2 = *reinterpret_cast<const __hip_bfloat162*>(&qb[addr]);
    __hip_bfloat162 k2 = *reinterpret_cast<const __hip_bfloat162*>(&kb[addr]);
    qv[r][0] = __bfloat162float(q2.x); qv[r][1] = __bfloat162float(q2.y);
    kv[r][0] = __bfloat162float(k2.x); kv[r][1] = __bfloat162float(k2.y);
    sq += qv[r][0] * qv[r][0] + qv[r][1] * qv[r][1];
    sk += kv[r][0] * kv[r][0] + kv[r][1] * kv[r][1];
  }
#pragma unroll
  for (int off = 1; off < 64; off <<= 1) {
    sq += __shfl_xor(sq, off);
    sk += __shfl_xor(sk, off);
  }
  __shared__ float red[2][4];
  if ((t & 63) == 0) { red[0][t >> 6] = sq; red[1][t >> 6] = sk; }
  __syncthreads();
  float tq = red[0][0] + red[0][1] + red[0][2] + red[0][3];
  float tk = red[1][0] + red[1][1] + red[1][2] + red[1][3];
  float rq = rsqrtf(tq * (1.0f / DMODEL) + 1e-6f);
  float rk = rsqrtf(tk * (1.0f / DMODEL) + 1e-6f);
  const float scale = 0.08838834764831845f; // 1/sqrt(128), folded into q
#pragma unroll
  for (int r = 0; r < 3; ++r) {
    int pi = t + r * 256;
    int head = pi >> 6;
    int dd = (pi & 63) * 2;
    int col = pi * 2;
    size_t addr = (((size_t)(b * NH + head)) * SEQ + s) * HD + dd;
    float q0 = qv[r][0] * rq * gq[col], q1 = qv[r][1] * rq * gq[col + 1];
    float k0 = kv[r][0] * rk * gk[col], k1 = kv[r][1] * rk * gk[col + 1];
    if (dorope) {
      int j = pi & 63;
      int row = (j < 22) ? fi : (j < 43) ? hi2 : wi;
      float co = fc[row * 64 + j], si = fs[row * 64 + j];
      float a;
      a = q0 * co - q1 * si; q1 = q0 * si + q1 * co; q0 = a;
      a = k0 * co - k1 * si; k1 = k0 * si + k1 * co; k0 = a;
    }
    q0 *= scale; q1 *= scale;
    __hip_bfloat162 oq, ok;
    oq.x = __float2bfloat16(q0); oq.y = __float2bfloat16(q1);
    ok.x = __float2bfloat16(k0); ok.y = __float2bfloat16(k1);
    *reinterpret_cast<__hip_bfloat162*>(&qb[addr]) = oq;
    *reinterpret_cast<__hip_bfloat162*>(&kb[addr]) = ok;
  }
}

// ---------- flash attention v2: 4 waves x QBLK=32 (128 q-rows/block), KVBLK=64 ----------
// K staged in LDS (double-buffered, XOR-swizzled via pre-swizzled global src);
// V read from global (L1/L2-resident); P in bf16 LDS; defer-max (T13).
__global__ __launch_bounds__(256, 3) void attn_kernel(
    const __hip_bfloat16* __restrict__ qb, const __hip_bfloat16* __restrict__ kbuf,
    const __hip_bfloat16* __restrict__ vt, const int* __restrict__ seq_lens,
    __hip_bfloat16* __restrict__ ob)
{
  const int qt = blockIdx.x, hh = blockIdx.y, bbb = blockIdx.z;
  const int bh = bbb * NH + hh;
  const int tid = threadIdx.x;
  const int w = tid >> 6, l = tid & 63;
  const int lr = l & 15, lg = l >> 4;
  const int sl = seq_lens[bbb];
  const __hip_bfloat16* Q = qb + (size_t)bh * SEQ * HD;
  const char* Kc = (const char*)(kbuf + (size_t)bh * SEQ * HD);
  const __hip_bfloat16* Vp = vt + (size_t)bh * HD * SEQ;   // [128][1792]
  const int q0 = qt * 128 + w * 32;

  __shared__ __hip_bfloat16 Kt[2][64 * 128];   // swizzled: byte ^= ((row&7)<<4)
  __shared__ __hip_bfloat16 Plb[4][32][72];    // per-wave P (bf16), padded

  bf16x8 aq[2][4];
#pragma unroll
  for (int fi = 0; fi < 2; ++fi)
#pragma unroll
    for (int kc = 0; kc < 4; ++kc)
      aq[fi][kc] = *reinterpret_cast<const bf16x8*>(
          &Q[(size_t)(q0 + fi * 16 + lr) * HD + kc * 32 + lg * 8]);

  f32x4 oacc[2][8] = {};
  float mrow[2][4] = {{-3e38f, -3e38f, -3e38f, -3e38f}, {-3e38f, -3e38f, -3e38f, -3e38f}};
  float lrow[2][4] = {{0.f, 0.f, 0.f, 0.f}, {0.f, 0.f, 0.f, 0.f}};

  const int nkt = (sl + 63) >> 6;

  auto stageK = [&](int buf, int k0) {
    char* Lb = (char*)&Kt[buf][0];
#pragma unroll
    for (int q = 0; q < 4; ++q) {
      int chunk = q * 256 + w * 64 + l;     // 16B chunk id in [0,1024)
      int row = chunk >> 4;                 // 16 chunks per 256B row
      int cb = (chunk & 15) << 4;
      int scb = cb ^ ((row & 7) << 4);      // inverse-swizzled source
      gload16(Kc + (size_t)(k0 + row) * 256 + scb, Lb + (q * 256 + w * 64) * 16);
    }
  };

  stageK(0, 0);
  for (int kt = 0; kt < nkt; ++kt) {
    __syncthreads();                         // stage(kt) drained; prev compute done
    const int k0 = kt * 64;
    if (kt + 1 < nkt) stageK((kt + 1) & 1, k0 + 64);
    const char* Kl = (const char*)&Kt[kt & 1][0];

    // QK^T: 16 swizzled ds_read_b128 + 32 MFMA
    f32x4 sa[2][4] = {};
#pragma unroll
    for (int cb4 = 0; cb4 < 4; ++cb4) {
      int row = cb4 * 16 + lr;
#pragma unroll
      for (int kc = 0; kc < 4; ++kc) {
        int cbyte = (kc * 64 + lg * 16) ^ ((lr & 7) << 4);
        bf16x8 bk8 = *reinterpret_cast<const bf16x8*>(Kl + row * 256 + cbyte);
        sa[0][cb4] = __builtin_amdgcn_mfma_f32_16x16x32_bf16(aq[0][kc], bk8, sa[0][cb4], 0, 0, 0);
        sa[1][cb4] = __builtin_amdgcn_mfma_f32_16x16x32_bf16(aq[1][kc], bk8, sa[1][cb4], 0, 0, 0);
      }
    }

    // online softmax per row-frag, defer-max (T13)
#pragma unroll
    for (int fi = 0; fi < 2; ++fi) {
      float pv[4][4];
      float mx[4] = {-3e38f, -3e38f, -3e38f, -3e38f};
#pragma unroll
      for (int cb4 = 0; cb4 < 4; ++cb4) {
        bool valid = (k0 + cb4 * 16 + lr) < sl;
#pragma unroll
        for (int r = 0; r < 4; ++r) {
          float sv = valid ? sa[fi][cb4][r] : -3e38f;
          pv[cb4][r] = sv;
          mx[r] = fmaxf(mx[r], sv);
        }
      }
#pragma unroll
      for (int off = 1; off < 16; off <<= 1)
#pragma unroll
        for (int r = 0; r < 4; ++r)
          mx[r] = fmaxf(mx[r], __shfl_xor(mx[r], off));
      bool ok = (mx[0] - mrow[fi][0] <= 8.f) && (mx[1] - mrow[fi][1] <= 8.f) &&
                (mx[2] - mrow[fi][2] <= 8.f) && (mx[3] - mrow[fi][3] <= 8.f);
      if (!__all(ok)) {
#pragma unroll
        for (int r = 0; r < 4; ++r) {
          float nm = fmaxf(mrow[fi][r], mx[r]);
          float a = __expf(mrow[fi][r] - nm);
          mrow[fi][r] = nm;
          lrow[fi][r] *= a;
#pragma unroll
          for (int df = 0; df < 8; ++df) oacc[fi][df][r] *= a;
        }
      }
      float rs[4] = {0.f, 0.f, 0.f, 0.f};
#pragma unroll
      for (int cb4 = 0; cb4 < 4; ++cb4)
#pragma unroll
        for (int r = 0; r < 4; ++r) {
          float e = __expf(pv[cb4][r] - mrow[fi][r]);
          rs[r] += e;
          Plb[w][fi * 16 + lg * 4 + r][cb4 * 16 + lr] = __float2bfloat16(e);
        }
#pragma unroll
      for (int off = 1; off < 16; off <<= 1)
#pragma unroll
        for (int r = 0; r < 4; ++r)
          rs[r] += __shfl_xor(rs[r], off);
#pragma unroll
      for (int r = 0; r < 4; ++r) lrow[fi][r] += rs[r];
    }

    // PV: P from LDS (b128), V from global
#pragma unroll
    for (int kc2 = 0; kc2 < 2; ++kc2) {
      bf16x8 pa0 = *reinterpret_cast<const bf16x8*>(&Plb[w][lr][kc2 * 32 + lg * 8]);
      bf16x8 pa1 = *reinterpret_cast<const bf16x8*>(&Plb[w][16 + lr][kc2 * 32 + lg * 8]);
#pragma unroll
      for (int df = 0; df < 8; ++df) {
        bf16x8 bv8 = *reinterpret_cast<const bf16x8*>(
            &Vp[(size_t)(df * 16 + lr) * SEQ + k0 + kc2 * 32 + lg * 8]);
        oacc[0][df] = __builtin_amdgcn_mfma_f32_16x16x32_bf16(pa0, bv8, oacc[0][df], 0, 0, 0);
        oacc[1][df] = __builtin_amdgcn_mfma_f32_16x16x32_bf16(pa1, bv8, oacc[1][df], 0, 0, 0);
      }
    }
  }

  float inv[2][4];
#pragma unroll
  for (int fi = 0; fi < 2; ++fi)
#pragma unroll
    for (int r = 0; r < 4; ++r) inv[fi][r] = 1.0f / lrow[fi][r];
#pragma unroll
  for (int fi = 0; fi < 2; ++fi)
#pragma unroll
    for (int df = 0; df < 8; ++df)
#pragma unroll
      for (int r = 0; r < 4; ++r) {
        int srow = q0 + fi * 16 + lg * 4 + r;
        int dcol = hh * HD + df * 16 + lr;
        ob[((size_t)bbb * SEQ + srow) * DMODEL + dcol] =
            __float2bfloat16(oacc[fi][df][r] * inv[fi][r]);
      }
}

// ---------- launch ----------
extern "C" void kernel_launch(void* const* d_in, const int* in_sizes, int n_in,
                              void* d_out, int out_size, void* d_ws, size_t ws_size,
                              hipStream_t stream) {
  const float* x   = (const float*)d_in[0];
  const int* seq_lens   = (const int*)d_in[1];
  const int* grid_sizes = (const int*)d_in[2];
  const float* fc  = (const float*)d_in[3];
  const float* fs  = (const float*)d_in[4];
  const float* Wq  = (const float*)d_in[5];
  const float* bq  = (const float*)d_in[6];
  const float* Wk  = (const float*)d_in[7];
  const float* bk  = (const float*)d_in[8];
  const float* Wv  = (const float*)d_in[9];
  const float* bv  = (const float*)d_in[10];
  const float* Wo  = (const float*)d_in[11];
  const float* bo  = (const float*)d_in[12];
  const float* gq  = (const float*)d_in[13];
  const float* gk  = (const float*)d_in[14];
  const int* nmod  = (const int*)d_in[15];
  float* out = (float*)d_out;

  char* ws = (char*)d_ws;
  __hip_bfloat16* xb   = (__hip_bfloat16*)(ws + 0);           // [7168][1536]
  __hip_bfloat16* wb   = (__hip_bfloat16*)(ws + 22020096);    // [4608][1536]
  __hip_bfloat16* wob  = (__hip_bfloat16*)(ws + 36175872);    // [1536][1536]
  __hip_bfloat16* qbuf = (__hip_bfloat16*)(ws + 40894464);    // [48][1792][128]
  __hip_bfloat16* kbuf = (__hip_bfloat16*)(ws + 62914560);    // [48][1792][128]
  __hip_bfloat16* vtb  = (__hip_bfloat16*)(ws + 84934656);    // [48][128][1792]
  __hip_bfloat16* ob   = xb;                                  // O reuses xb region

  cast_kernel<<<(11010048 / 4 + 255) / 256, 256, 0, stream>>>(x, xb, 11010048 / 4);
  cast_kernel<<<(2359296 / 4 + 255) / 256, 256, 0, stream>>>(Wq, wb, 2359296 / 4);
  cast_kernel<<<(2359296 / 4 + 255) / 256, 256, 0, stream>>>(Wk, wb + 2359296, 2359296 / 4);
  cast_kernel<<<(2359296 / 4 + 255) / 256, 256, 0, stream>>>(Wv, wb + 4718592, 2359296 / 4);
  cast_kernel<<<(2359296 / 4 + 255) / 256, 256, 0, stream>>>(Wo, wob, 2359296 / 4);

  gemm_bt<0><<<dim3(36, 56), 256, 0, stream>>>(xb, wb, 1536, bq, bk, bv,
                                               qbuf, kbuf, vtb, nullptr, nullptr);
  rmsrope_kernel<<<7168, 256, 0, stream>>>(qbuf, kbuf, gq, gk, fc, fs, grid_sizes, nmod);
  attn_kernel<<<dim3(14, 12, 4), 256, 0, stream>>>(qbuf, kbuf, vtb, seq_lens, ob);
  gemm_bt<1><<<dim3(12, 56), 256, 0, stream>>>(ob, wob, 1536, nullptr, nullptr, nullptr,
                                               nullptr, nullptr, nullptr, bo, out);
}

// Round 3
// 540.812 us; speedup vs baseline: 1.6866x; 1.2293x over previous
//
#include <hip/hip_runtime.h>
#include <hip/hip_bf16.h>

typedef short bf16x8 __attribute__((ext_vector_type(8)));
typedef float f32x4 __attribute__((ext_vector_type(4)));
typedef float f32x16 __attribute__((ext_vector_type(16)));

#define NH 12
#define SEQ 1792
#define DMODEL 1536
#define HD 128

static __device__ __forceinline__ void gload16(const void* g, void* l) {
  __builtin_amdgcn_global_load_lds((const __attribute__((address_space(1))) void*)g,
                                   (__attribute__((address_space(3))) void*)l, 16, 0, 0);
}

static __device__ __forceinline__ short f2bf(float x) {
  __hip_bfloat16 h = __float2bfloat16(x);
  return *reinterpret_cast<short*>(&h);
}

static __device__ __forceinline__ unsigned pack2(float lo, float hi) {
  unsigned a = (unsigned)(unsigned short)f2bf(lo);
  unsigned b = (unsigned)(unsigned short)f2bf(hi);
  return a | (b << 16);
}

// ---------- fp32 -> bf16 cast, x4 vectorized ----------
__global__ __launch_bounds__(256) void cast_kernel(const float* __restrict__ src,
                                                   __hip_bfloat16* __restrict__ dst, int n4) {
  int i = blockIdx.x * 256 + threadIdx.x;
  if (i >= n4) return;
  float4 v = reinterpret_cast<const float4*>(src)[i];
  short4 r;
  r.x = f2bf(v.x); r.y = f2bf(v.y); r.z = f2bf(v.z); r.w = f2bf(v.w);
  reinterpret_cast<short4*>(dst)[i] = r;
}

// ---------- 128x128 bf16 GEMM, B^T layout (C = A @ B^T), m97 structure ----------
template<int MODE>
__global__ __launch_bounds__(256) void gemm_bt(
    const __hip_bfloat16* __restrict__ A, const __hip_bfloat16* __restrict__ B, int K,
    const float* __restrict__ bq, const float* __restrict__ bk, const float* __restrict__ bv,
    __hip_bfloat16* __restrict__ qbuf, __hip_bfloat16* __restrict__ kbuf,
    __hip_bfloat16* __restrict__ vt,
    const float* __restrict__ bo, float* __restrict__ outp)
{
  __shared__ __hip_bfloat16 Abuf[2][128 * 32];
  __shared__ __hip_bfloat16 Bbuf[2][128 * 32];
  const int tid = threadIdx.x;
  const int l = tid & 63, w = tid >> 6;
  const int lr = l & 15, lg = l >> 4;
  const int wr = w >> 1, wc = w & 1;
  const int m0 = blockIdx.y * 128, n0 = blockIdx.x * 128;
  const int nK = K >> 5;

  f32x4 acc[4][4] = {};

  auto stage = [&](int buf, int kk) {
#pragma unroll
    for (int q2 = 0; q2 < 2; ++q2) {
      int flat = q2 * 256 + tid;
      int row = flat >> 2;
      int kb16 = (flat & 3) * 16;
      const __hip_bfloat16* ga = A + (size_t)(m0 + row) * K + kk + (kb16 >> 1);
      gload16(ga, &Abuf[buf][(q2 * 256 + w * 64) * 8]);
      const __hip_bfloat16* gb = B + (size_t)(n0 + row) * K + kk + (kb16 >> 1);
      gload16(gb, &Bbuf[buf][(q2 * 256 + w * 64) * 8]);
    }
  };

  stage(0, 0);
  for (int kt = 0; kt < nK; ++kt) {
    __syncthreads();
    if (kt + 1 < nK) stage((kt + 1) & 1, (kt + 1) * 32);
    const __hip_bfloat16* Ab = Abuf[kt & 1];
    const __hip_bfloat16* Bb = Bbuf[kt & 1];
    bf16x8 af[4], bfr[4];
#pragma unroll
    for (int fi = 0; fi < 4; ++fi)
      af[fi] = *reinterpret_cast<const bf16x8*>(&Ab[(wr * 64 + fi * 16 + lr) * 32 + lg * 8]);
#pragma unroll
    for (int fj = 0; fj < 4; ++fj)
      bfr[fj] = *reinterpret_cast<const bf16x8*>(&Bb[(wc * 64 + fj * 16 + lr) * 32 + lg * 8]);
#pragma unroll
    for (int fi = 0; fi < 4; ++fi)
#pragma unroll
      for (int fj = 0; fj < 4; ++fj)
        acc[fi][fj] = __builtin_amdgcn_mfma_f32_16x16x32_bf16(af[fi], bfr[fj], acc[fi][fj], 0, 0, 0);
  }

  if (MODE == 0) {
#pragma unroll
    for (int fj = 0; fj < 4; ++fj) {
      int ncol = n0 + wc * 64 + fj * 16 + lr;
      int which = ncol / DMODEL;
      int cc = ncol - which * DMODEL;
      int hh = cc >> 7, dd = cc & 127;
      float bias = (which == 0 ? bq : which == 1 ? bk : bv)[cc];
#pragma unroll
      for (int fi = 0; fi < 4; ++fi)
#pragma unroll
        for (int r = 0; r < 4; ++r) {
          int rowg = m0 + wr * 64 + fi * 16 + lg * 4 + r;
          int bbb = rowg / SEQ;
          int sr = rowg - bbb * SEQ;
          __hip_bfloat16 hv = __float2bfloat16(acc[fi][fj][r] + bias);
          if (which == 0)
            qbuf[(((size_t)(bbb * NH + hh)) * SEQ + sr) * HD + dd] = hv;
          else if (which == 1)
            kbuf[(((size_t)(bbb * NH + hh)) * SEQ + sr) * HD + dd] = hv;
          else
            vt[(((size_t)(bbb * NH + hh)) * HD + dd) * SEQ + sr] = hv;
        }
    }
  } else {
#pragma unroll
    for (int fj = 0; fj < 4; ++fj) {
      int ncol = n0 + wc * 64 + fj * 16 + lr;
      float bias = bo[ncol];
#pragma unroll
      for (int fi = 0; fi < 4; ++fi)
#pragma unroll
        for (int r = 0; r < 4; ++r) {
          int rowg = m0 + wr * 64 + fi * 16 + lg * 4 + r;
          outp[(size_t)rowg * DMODEL + ncol] = acc[fi][fj][r] + bias;
        }
    }
  }
}

// ---------- RMSNorm (full-D) + 3D-grid RoPE, in-place on q,k ----------
// q additionally pre-scaled by 1/sqrt(HD) so attention skips the scale.
__global__ __launch_bounds__(256) void rmsrope_kernel(
    __hip_bfloat16* __restrict__ qb, __hip_bfloat16* __restrict__ kb,
    const float* __restrict__ gq, const float* __restrict__ gk,
    const float* __restrict__ fc, const float* __restrict__ fs,
    const int* __restrict__ gsz, const int* __restrict__ nmod)
{
  const int bs = blockIdx.x;
  const int b = bs / SEQ, s = bs - b * SEQ;
  const int t = threadIdx.x;
  const int f = gsz[0], h = gsz[1], wd = gsz[2];
  const int mm = nmod[0];
  const int seq_per = f * h * wd;
  int total_len = seq_per * mm; if (total_len > SEQ) total_len = SEQ;
  const bool dorope = s < total_len;
  int fi = 0, hi2 = 0, wi = 0;
  if (dorope) {
    int p = s % seq_per;
    fi = p / (h * wd);
    int rem = p - fi * (h * wd);
    hi2 = rem / wd;
    wi = rem - hi2 * wd;
  }
  float qv[3][2], kv[3][2];
  float sq = 0.f, sk = 0.f;
#pragma unroll
  for (int r = 0; r < 3; ++r) {
    int pi = t + r * 256;
    int head = pi >> 6;
    int dd = (pi & 63) * 2;
    size_t addr = (((size_t)(b * NH + head)) * SEQ + s) * HD + dd;
    __hip_bfloat162 q2 = *reinterpret_cast<const __hip_bfloat162*>(&qb[addr]);
    __hip_bfloat162 k2 = *reinterpret_cast<const __hip_bfloat162*>(&kb[addr]);
    qv[r][0] = __bfloat162float(q2.x); qv[r][1] = __bfloat162float(q2.y);
    kv[r][0] = __bfloat162float(k2.x); kv[r][1] = __bfloat162float(k2.y);
    sq += qv[r][0] * qv[r][0] + qv[r][1] * qv[r][1];
    sk += kv[r][0] * kv[r][0] + kv[r][1] * kv[r][1];
  }
#pragma unroll
  for (int off = 1; off < 64; off <<= 1) {
    sq += __shfl_xor(sq, off);
    sk += __shfl_xor(sk, off);
  }
  __shared__ float red[2][4];
  if ((t & 63) == 0) { red[0][t >> 6] = sq; red[1][t >> 6] = sk; }
  __syncthreads();
  float tq = red[0][0] + red[0][1] + red[0][2] + red[0][3];
  float tk = red[1][0] + red[1][1] + red[1][2] + red[1][3];
  float rq = rsqrtf(tq * (1.0f / DMODEL) + 1e-6f);
  float rk = rsqrtf(tk * (1.0f / DMODEL) + 1e-6f);
  const float scale = 0.08838834764831845f; // 1/sqrt(128), folded into q
#pragma unroll
  for (int r = 0; r < 3; ++r) {
    int pi = t + r * 256;
    int head = pi >> 6;
    int dd = (pi & 63) * 2;
    int col = pi * 2;
    size_t addr = (((size_t)(b * NH + head)) * SEQ + s) * HD + dd;
    float q0 = qv[r][0] * rq * gq[col], q1 = qv[r][1] * rq * gq[col + 1];
    float k0 = kv[r][0] * rk * gk[col], k1 = kv[r][1] * rk * gk[col + 1];
    if (dorope) {
      int j = pi & 63;
      int row = (j < 22) ? fi : (j < 43) ? hi2 : wi;
      float co = fc[row * 64 + j], si = fs[row * 64 + j];
      float a;
      a = q0 * co - q1 * si; q1 = q0 * si + q1 * co; q0 = a;
      a = k0 * co - k1 * si; k1 = k0 * si + k1 * co; k0 = a;
    }
    q0 *= scale; q1 *= scale;
    __hip_bfloat162 oq, ok;
    oq.x = __float2bfloat16(q0); oq.y = __float2bfloat16(q1);
    ok.x = __float2bfloat16(k0); ok.y = __float2bfloat16(k1);
    *reinterpret_cast<__hip_bfloat162*>(&qb[addr]) = oq;
    *reinterpret_cast<__hip_bfloat162*>(&kb[addr]) = ok;
  }
}

// ---------- flash attention v3: 8 waves x QBLK=32 (256 q-rows/block) ----------
// Swapped QK^T (mfma(K,Q) -> lane owns one q-row), in-register softmax (T12-style
// pack via shfl_xor(32)), defer-max (T13), K LDS dbuf XOR-swizzled, V direct
// global (contiguous via V^T), bijective XCD swizzle (T1/m204).
__global__ __launch_bounds__(512, 2) void attn_kernel(
    const __hip_bfloat16* __restrict__ qb, const __hip_bfloat16* __restrict__ kbuf,
    const __hip_bfloat16* __restrict__ vt, const int* __restrict__ seq_lens,
    __hip_bfloat16* __restrict__ ob)
{
  // nwg = 336 = 8 * 42: xcd-contiguous remap (6 whole heads per XCD)
  const int orig = blockIdx.x;
  const int wg = (orig & 7) * 42 + (orig >> 3);
  const int bh = wg / 7, qt = wg % 7;
  const int bbb = bh / NH, hh = bh - bbb * NH;
  const int tid = threadIdx.x;
  const int w = tid >> 6, l = tid & 63;
  const int lq = l & 31, h = l >> 5;
  const int sl = seq_lens[bbb];
  const __hip_bfloat16* Q = qb + (size_t)bh * SEQ * HD;
  const char* Kc = (const char*)(kbuf + (size_t)bh * SEQ * HD);
  const __hip_bfloat16* Vp = vt + (size_t)bh * HD * SEQ;   // [128][1792]
  const int q0 = qt * 256 + w * 32;

  __shared__ __hip_bfloat16 Kt[2][64 * 128];   // swizzled: byte ^= ((row&7)<<4)

  // Q fragments (B-operand of swapped QK^T): lane holds Q[q0+lq][kc*16 + h*8 + j]
  bf16x8 qf[8];
#pragma unroll
  for (int kc = 0; kc < 8; ++kc)
    qf[kc] = *reinterpret_cast<const bf16x8*>(
        &Q[(size_t)(q0 + lq) * HD + kc * 16 + h * 8]);

  f32x16 oacc[4] = {};                          // O[q_off][d0*32+lq]
  float m = -3e38f, ll = 0.f;                   // per-lane q-row softmax state

  const int nkt = (sl + 63) >> 6;

  auto stageK = [&](int buf, int k0) {
    char* Lb = (char*)&Kt[buf][0];
#pragma unroll
    for (int q2 = 0; q2 < 2; ++q2) {
      int chunk = q2 * 512 + w * 64 + l;        // 16B chunk id in [0,1024)
      int row = chunk >> 4;                     // 16 chunks per 256B row
      int cb = (chunk & 15) << 4;
      int scb = cb ^ ((row & 7) << 4);          // inverse-swizzled source
      gload16(Kc + (size_t)(k0 + row) * 256 + scb, Lb + (q2 * 512 + w * 64) * 16);
    }
  };

  stageK(0, 0);
  for (int kt = 0; kt < nkt; ++kt) {
    __syncthreads();                            // stage(kt) drained
    const int k0 = kt * 64;
    if (kt + 1 < nkt) stageK((kt + 1) & 1, k0 + 64);
    const char* Kl = (const char*)&Kt[kt & 1][0];

    // swapped QK^T: S^T[k][q], 16 ds_read_b128 + 16 mfma_32x32x16
    f32x16 sa[2] = {};
#pragma unroll
    for (int cb = 0; cb < 2; ++cb) {
      int row = cb * 32 + lq;
      int swz = (row & 7) << 4;
#pragma unroll
      for (int kc = 0; kc < 8; ++kc) {
        bf16x8 kf = *reinterpret_cast<const bf16x8*>(
            Kl + row * 256 + ((kc * 32 + h * 16) ^ swz));
        sa[cb] = __builtin_amdgcn_mfma_f32_32x32x16_bf16(kf, qf[kc], sa[cb], 0, 0, 0);
      }
    }

    // mask tail (rare): k of sa[cb][r] = k0 + cb*32 + (r&3) + 8*(r>>2) + 4*h
    if (k0 + 64 > sl) {
#pragma unroll
      for (int cb = 0; cb < 2; ++cb)
#pragma unroll
        for (int r = 0; r < 16; ++r) {
          int kg = k0 + cb * 32 + (r & 3) + 8 * (r >> 2) + 4 * h;
          if (kg >= sl) sa[cb][r] = -3e38f;
        }
    }

    // in-register online softmax: lane owns q-row (lq), halves split across h
    float mx = -3e38f;
#pragma unroll
    for (int cb = 0; cb < 2; ++cb)
#pragma unroll
      for (int r = 0; r < 16; ++r) mx = fmaxf(mx, sa[cb][r]);
    mx = fmaxf(mx, __shfl_xor(mx, 32));

    if (__any(mx - m > 8.f)) {                  // defer-max (T13)
      float mn = fmaxf(m, mx);
      float alpha = __expf(m - mn);
      m = mn;
      ll *= alpha;
#pragma unroll
      for (int r = 0; r < 16; ++r) {
        float ar = __shfl(alpha, (r & 3) + 8 * (r >> 2) + 4 * h);
#pragma unroll
        for (int d0 = 0; d0 < 4; ++d0) oacc[d0][r] *= ar;
      }
    }

    float rs = 0.f;
#pragma unroll
    for (int cb = 0; cb < 2; ++cb)
#pragma unroll
      for (int r = 0; r < 16; ++r) {
        float e = __expf(sa[cb][r] - m);
        sa[cb][r] = e;
        rs += e;
      }
    rs += __shfl_xor(rs, 32);
    ll += rs;

    // P -> bf16 A-frags (pack + shfl_xor(32) exchange) and PV
#pragma unroll
    for (int c = 0; c < 4; ++c) {
      const int cb = c >> 1, r0 = 8 * (c & 1);
      unsigned A01 = pack2(sa[cb][r0],     sa[cb][r0 + 1]);
      unsigned A23 = pack2(sa[cb][r0 + 2], sa[cb][r0 + 3]);
      unsigned B01 = pack2(sa[cb][r0 + 4], sa[cb][r0 + 5]);
      unsigned B23 = pack2(sa[cb][r0 + 6], sa[cb][r0 + 7]);
      unsigned s1 = __shfl_xor(h ? A01 : B01, 32);
      unsigned s2 = __shfl_xor(h ? A23 : B23, 32);
      int4 wv;
      wv.x = (int)(h ? s1 : A01);
      wv.y = (int)(h ? s2 : A23);
      wv.z = (int)(h ? B01 : s1);
      wv.w = (int)(h ? B23 : s2);
      bf16x8 pa = *reinterpret_cast<bf16x8*>(&wv);
#pragma unroll
      for (int d0 = 0; d0 < 4; ++d0) {
        bf16x8 vv = *reinterpret_cast<const bf16x8*>(
            &Vp[(size_t)(d0 * 32 + lq) * SEQ + k0 + c * 16 + h * 8]);
        oacc[d0] = __builtin_amdgcn_mfma_f32_32x32x16_bf16(pa, vv, oacc[d0], 0, 0, 0);
      }
    }
  }

  // epilogue: normalize by per-q-row sum, write O
  float invl = 1.0f / ll;
#pragma unroll
  for (int r = 0; r < 16; ++r) {
    int qoff = (r & 3) + 8 * (r >> 2) + 4 * h;
    float ir = __shfl(invl, qoff);
    int qrow = q0 + qoff;
#pragma unroll
    for (int d0 = 0; d0 < 4; ++d0)
      ob[((size_t)bbb * SEQ + qrow) * DMODEL + hh * HD + d0 * 32 + lq] =
          __float2bfloat16(oacc[d0][r] * ir);
  }
}

// ---------- launch ----------
extern "C" void kernel_launch(void* const* d_in, const int* in_sizes, int n_in,
                              void* d_out, int out_size, void* d_ws, size_t ws_size,
                              hipStream_t stream) {
  const float* x   = (const float*)d_in[0];
  const int* seq_lens   = (const int*)d_in[1];
  const int* grid_sizes = (const int*)d_in[2];
  const float* fc  = (const float*)d_in[3];
  const float* fs  = (const float*)d_in[4];
  const float* Wq  = (const float*)d_in[5];
  const float* bq  = (const float*)d_in[6];
  const float* Wk  = (const float*)d_in[7];
  const float* bk  = (const float*)d_in[8];
  const float* Wv  = (const float*)d_in[9];
  const float* bv  = (const float*)d_in[10];
  const float* Wo  = (const float*)d_in[11];
  const float* bo  = (const float*)d_in[12];
  const float* gq  = (const float*)d_in[13];
  const float* gk  = (const float*)d_in[14];
  const int* nmod  = (const int*)d_in[15];
  float* out = (float*)d_out;

  char* ws = (char*)d_ws;
  __hip_bfloat16* xb   = (__hip_bfloat16*)(ws + 0);           // [7168][1536]
  __hip_bfloat16* wb   = (__hip_bfloat16*)(ws + 22020096);    // [4608][1536]
  __hip_bfloat16* wob  = (__hip_bfloat16*)(ws + 36175872);    // [1536][1536]
  __hip_bfloat16* qbuf = (__hip_bfloat16*)(ws + 40894464);    // [48][1792][128]
  __hip_bfloat16* kbuf = (__hip_bfloat16*)(ws + 62914560);    // [48][1792][128]
  __hip_bfloat16* vtb  = (__hip_bfloat16*)(ws + 84934656);    // [48][128][1792]
  __hip_bfloat16* ob   = xb;                                  // O reuses xb region

  cast_kernel<<<(11010048 / 4 + 255) / 256, 256, 0, stream>>>(x, xb, 11010048 / 4);
  cast_kernel<<<(2359296 / 4 + 255) / 256, 256, 0, stream>>>(Wq, wb, 2359296 / 4);
  cast_kernel<<<(2359296 / 4 + 255) / 256, 256, 0, stream>>>(Wk, wb + 2359296, 2359296 / 4);
  cast_kernel<<<(2359296 / 4 + 255) / 256, 256, 0, stream>>>(Wv, wb + 4718592, 2359296 / 4);
  cast_kernel<<<(2359296 / 4 + 255) / 256, 256, 0, stream>>>(Wo, wob, 2359296 / 4);

  gemm_bt<0><<<dim3(36, 56), 256, 0, stream>>>(xb, wb, 1536, bq, bk, bv,
                                               qbuf, kbuf, vtb, nullptr, nullptr);
  rmsrope_kernel<<<7168, 256, 0, stream>>>(qbuf, kbuf, gq, gk, fc, fs, grid_sizes, nmod);
  attn_kernel<<<336, 512, 0, stream>>>(qbuf, kbuf, vtb, seq_lens, ob);
  gemm_bt<1><<<dim3(12, 56), 256, 0, stream>>>(ob, wob, 1536, nullptr, nullptr, nullptr,
                                               nullptr, nullptr, nullptr, bo, out);
}